// Round 1
// baseline (193.532 us; speedup 1.0000x reference)
//
#include <hip/hip_runtime.h>
#include <math.h>

#define B_ROWS 4096
#define T_COLS 4096
#define L_CHUNK 64
#define K_CHUNKS (T_COLS / L_CHUNK)   // 64 chunks per row

// Affine-map parameters derived from the three log-scalars (device-resident).
__device__ inline void get_params(const float* p_omega_log, const float* p_alpha_log,
                                  const float* p_beta_log,
                                  float& omega, float& alpha, float& beta) {
    float ea = expf(p_alpha_log[0]);
    float eb = expf(p_beta_log[0]);
    float denom = 1.0f + ea + eb;
    omega = expf(p_omega_log[0]);
    alpha = ea / denom;
    beta  = eb / denom;
}

// Kernel A: one thread per (row, chunk). Computes chunk sum / sumsq (for the
// row variance) and the chunk's zero-init recurrence partial B_j.
// Chunk j covers output timesteps t in [j*64, (j+1)*64); recurrence input for
// step t is x[t-1]. Chunk 0's t=0 is s0 itself (no recurrence step).
__global__ __launch_bounds__(256) void garch_partials(
    const float* __restrict__ x,
    const float* __restrict__ p_omega_log, const float* __restrict__ p_alpha_log,
    const float* __restrict__ p_beta_log,
    float* __restrict__ sumP, float* __restrict__ ssqP, float* __restrict__ Bp)
{
    int g = blockIdx.x * blockDim.x + threadIdx.x;      // (b*K_CHUNKS + j)
    int b = g >> 6;
    int j = g & (K_CHUNKS - 1);

    float omega, alpha, beta;
    get_params(p_omega_log, p_alpha_log, p_beta_log, omega, alpha, beta);

    long base = (long)b * T_COLS + (long)j * L_CHUNK;
    const float4* xv = reinterpret_cast<const float4*>(x + base);

    float prev = (j > 0) ? x[base - 1] : 0.0f;
    float s = 0.0f, sum = 0.0f, ssq = 0.0f;

#pragma unroll
    for (int i = 0; i < L_CHUNK / 4; ++i) {
        float4 v = xv[i];
        sum += (v.x + v.y) + (v.z + v.w);
        ssq += (v.x * v.x + v.y * v.y) + (v.z * v.z + v.w * v.w);
        if (j == 0 && i == 0) {
            // outputs t=1,2,3 (t=0 is s0): inputs x0,x1,x2
            s = fmaf(alpha, v.x * v.x, omega);                     // s was 0
            s = fmaf(beta, s, fmaf(alpha, v.y * v.y, omega));
            s = fmaf(beta, s, fmaf(alpha, v.z * v.z, omega));
        } else {
            s = fmaf(beta, s, fmaf(alpha, prev * prev, omega));
            s = fmaf(beta, s, fmaf(alpha, v.x * v.x, omega));
            s = fmaf(beta, s, fmaf(alpha, v.y * v.y, omega));
            s = fmaf(beta, s, fmaf(alpha, v.z * v.z, omega));
        }
        prev = v.w;
    }
    sumP[g] = sum;
    ssqP[g] = ssq;
    Bp[g]   = s;
}

// Kernel B: one thread per row. Reduce chunk partials -> s0 (unbiased var),
// then serially compose the K affine maps to produce each chunk's entry state
// entry[j] = sigma2_{j*64 - 1} (entry[0] = s0 = sigma2_0).
__global__ __launch_bounds__(256) void garch_combine(
    const float* __restrict__ sumP, const float* __restrict__ ssqP,
    const float* __restrict__ Bp,
    const float* __restrict__ p_omega_log, const float* __restrict__ p_alpha_log,
    const float* __restrict__ p_beta_log,
    float* __restrict__ entry)
{
    int b = blockIdx.x * blockDim.x + threadIdx.x;
    if (b >= B_ROWS) return;

    float omega, alpha, beta;
    get_params(p_omega_log, p_alpha_log, p_beta_log, omega, alpha, beta);
    (void)omega; (void)alpha;

    const float4* sp = reinterpret_cast<const float4*>(sumP + (long)b * K_CHUNKS);
    const float4* qp = reinterpret_cast<const float4*>(ssqP + (long)b * K_CHUNKS);
    float sum = 0.0f, ssq = 0.0f;
#pragma unroll
    for (int i = 0; i < K_CHUNKS / 4; ++i) {
        float4 v = sp[i];
        float4 w = qp[i];
        sum += (v.x + v.y) + (v.z + v.w);
        ssq += (w.x + w.y) + (w.z + w.w);
    }
    float s0 = (ssq - sum * sum * (1.0f / T_COLS)) * (1.0f / (T_COLS - 1));
    s0 = fmaxf(s0, 0.0f);

    float A  = powf(beta, (float)L_CHUNK);        // beta^64
    float A0 = powf(beta, (float)(L_CHUNK - 1));  // chunk 0 has 63 steps

    const float* Bb = Bp + (long)b * K_CHUNKS;
    float* eb = entry + (long)b * K_CHUNKS;

    eb[0] = s0;
    float carry = fmaf(A0, s0, Bb[0]);            // exit state of chunk 0
    for (int j = 1; j < K_CHUNKS; ++j) {
        eb[j] = carry;
        carry = fmaf(A, carry, Bb[j]);
    }
}

// Kernel C: one thread per (row, chunk). Re-run chunk from its entry state,
// write sqrt(sigma2) with float4 stores.
__global__ __launch_bounds__(256) void garch_final(
    const float* __restrict__ x,
    const float* __restrict__ p_omega_log, const float* __restrict__ p_alpha_log,
    const float* __restrict__ p_beta_log,
    const float* __restrict__ entry,
    float* __restrict__ out)
{
    int g = blockIdx.x * blockDim.x + threadIdx.x;
    int b = g >> 6;
    int j = g & (K_CHUNKS - 1);

    float omega, alpha, beta;
    get_params(p_omega_log, p_alpha_log, p_beta_log, omega, alpha, beta);

    long base = (long)b * T_COLS + (long)j * L_CHUNK;
    const float4* xv = reinterpret_cast<const float4*>(x + base);
    float4* ov = reinterpret_cast<float4*>(out + base);

    float prev = (j > 0) ? x[base - 1] : 0.0f;
    float s = entry[g];

#pragma unroll
    for (int i = 0; i < L_CHUNK / 4; ++i) {
        float4 v = xv[i];
        float4 o;
        if (j == 0 && i == 0) {
            o.x = sqrtf(s);                                        // t=0: s0
            s = fmaf(beta, s, fmaf(alpha, v.x * v.x, omega)); o.y = sqrtf(s);
            s = fmaf(beta, s, fmaf(alpha, v.y * v.y, omega)); o.z = sqrtf(s);
            s = fmaf(beta, s, fmaf(alpha, v.z * v.z, omega)); o.w = sqrtf(s);
        } else {
            s = fmaf(beta, s, fmaf(alpha, prev * prev, omega)); o.x = sqrtf(s);
            s = fmaf(beta, s, fmaf(alpha, v.x * v.x, omega));   o.y = sqrtf(s);
            s = fmaf(beta, s, fmaf(alpha, v.y * v.y, omega));   o.z = sqrtf(s);
            s = fmaf(beta, s, fmaf(alpha, v.z * v.z, omega));   o.w = sqrtf(s);
        }
        prev = v.w;
        ov[i] = o;
    }
}

extern "C" void kernel_launch(void* const* d_in, const int* in_sizes, int n_in,
                              void* d_out, int out_size, void* d_ws, size_t ws_size,
                              hipStream_t stream) {
    const float* x           = (const float*)d_in[0];
    const float* omega_log   = (const float*)d_in[1];
    const float* alpha_log   = (const float*)d_in[2];
    const float* beta_log    = (const float*)d_in[3];
    float* out = (float*)d_out;

    float* ws = (float*)d_ws;
    const long NP = (long)B_ROWS * K_CHUNKS;      // 262144
    float* sumP  = ws;
    float* ssqP  = ws + NP;
    float* Bp    = ws + 2 * NP;
    float* entry = ws + 3 * NP;                    // total 4 MB of ws

    const int nchunks = B_ROWS * K_CHUNKS;
    dim3 blk(256);

    garch_partials<<<nchunks / 256, blk, 0, stream>>>(
        x, omega_log, alpha_log, beta_log, sumP, ssqP, Bp);
    garch_combine<<<B_ROWS / 256, blk, 0, stream>>>(
        sumP, ssqP, Bp, omega_log, alpha_log, beta_log, entry);
    garch_final<<<nchunks / 256, blk, 0, stream>>>(
        x, omega_log, alpha_log, beta_log, entry, out);
}

// Round 2
// 115.506 us; speedup vs baseline: 1.6755x; 1.6755x over previous
//
#include <hip/hip_runtime.h>
#include <math.h>

#define B_ROWS 4096
#define T_COLS 4096
#define NTHREADS 256
#define CHUNK 16                 // elements per thread
#define NWAVES (NTHREADS / 64)   // 4

// Padded LDS addressing: +1 float per 16-float chunk -> 2-way bank conflicts only.
__device__ __forceinline__ int paddr(int e) { return e + (e >> 4); }
#define LDS_FLOATS (T_COLS + (T_COLS >> 4))   // 4096 + 256 = 4352

__global__ __launch_bounds__(NTHREADS) void garch_fused(
    const float* __restrict__ x,
    const float* __restrict__ p_omega_log,
    const float* __restrict__ p_alpha_log,
    const float* __restrict__ p_beta_log,
    float* __restrict__ out)
{
    __shared__ float lds[LDS_FLOATS];
    __shared__ float wA[NWAVES], wB[NWAVES];
    __shared__ float rSum[NWAVES], rSsq[NWAVES];

    const int t    = threadIdx.x;
    const int lane = t & 63;
    const int wv   = t >> 6;
    const int row  = blockIdx.x;
    const long rbase = (long)row * T_COLS;

    // Parameters (uniform scalar work)
    float ea = expf(p_alpha_log[0]);
    float eb = expf(p_beta_log[0]);
    float denom = 1.0f + ea + eb;
    float omega = expf(p_omega_log[0]);
    float alpha = ea / denom;
    float beta  = eb / denom;
    float b2 = beta * beta, b4 = b2 * b2, b8 = b4 * b4, b16 = b8 * b8;

    // ---- Phase 0: coalesced global -> padded LDS ----
    const float4* xv = reinterpret_cast<const float4*>(x + rbase);
#pragma unroll
    for (int k = 0; k < 4; ++k) {
        int e4 = k * 1024 + 4 * t;            // float index of this float4
        float4 v = xv[k * 256 + t];
        int a0 = paddr(e4);                   // 4 elements stay inside one chunk
        lds[a0 + 0] = v.x; lds[a0 + 1] = v.y; lds[a0 + 2] = v.z; lds[a0 + 3] = v.w;
    }
    __syncthreads();

    // ---- Phase 1: per-thread chunk -> registers; sum/ssq + affine partial ----
    float xr[CHUNK];
    int cbase = 17 * t;                        // paddr(16*t)
#pragma unroll
    for (int i = 0; i < CHUNK; ++i) xr[i] = lds[cbase + i];
    float prev = (t > 0) ? lds[paddr(CHUNK * t - 1)] : 0.0f;

    float sum = 0.0f, ssq = 0.0f;
#pragma unroll
    for (int i = 0; i < CHUNK; ++i) { sum += xr[i]; ssq = fmaf(xr[i], xr[i], ssq); }

    // Zero-init recurrence partial B_t.
    // Thread 0: 15 steps (inputs x0..x14, outputs sigma2_1..15), A = beta^15.
    // Thread t>0: 16 steps (inputs x[16t-1]=prev, xr[0..14]),   A = beta^16.
    float bpart = 0.0f;
    if (t > 0) bpart = fmaf(alpha, prev * prev, omega);   // first step (s was 0)
#pragma unroll
    for (int i = 0; i < CHUNK - 1; ++i)
        bpart = fmaf(beta, bpart, fmaf(alpha, xr[i] * xr[i], omega));
    float apart = (t == 0) ? (b8 * b4 * b2 * beta) : b16;

    // ---- Phase 2a: block reduction -> s0 ----
    float s1 = sum, s2 = ssq;
#pragma unroll
    for (int d = 32; d > 0; d >>= 1) {
        s1 += __shfl_xor(s1, d);
        s2 += __shfl_xor(s2, d);
    }
    if (lane == 0) { rSum[wv] = s1; rSsq[wv] = s2; }
    __syncthreads();
    float tsum = rSum[0] + rSum[1] + rSum[2] + rSum[3];
    float tssq = rSsq[0] + rSsq[1] + rSsq[2] + rSsq[3];
    float s0 = (tssq - tsum * tsum * (1.0f / T_COLS)) * (1.0f / (T_COLS - 1));
    s0 = fmaxf(s0, 0.0f);

    // ---- Phase 2b: block-wide affine scan (f_t(s) = apart*s + bpart) ----
    float ia = apart, ib = bpart;
#pragma unroll
    for (int d = 1; d < 64; d <<= 1) {
        float pa = __shfl_up(ia, d);
        float pb = __shfl_up(ib, d);
        if (lane >= d) { ib = fmaf(ia, pb, ib); ia = ia * pa; }
    }
    if (lane == 63) { wA[wv] = ia; wB[wv] = ib; }
    __syncthreads();
    float sw = s0;
#pragma unroll
    for (int w = 0; w < NWAVES - 1; ++w)
        if (w < wv) sw = fmaf(wA[w], sw, wB[w]);
    // exclusive intra-wave prefix
    float ea_ = __shfl_up(ia, 1);
    float eb_ = __shfl_up(ib, 1);
    if (lane == 0) { ea_ = 1.0f; eb_ = 0.0f; }
    float s = fmaf(ea_, sw, eb_);              // entry state sigma2_{16t-1} (or s0 for t==0)

    // ---- Phase 3: replay chunk, sqrt -> LDS (transposed back) ----
    // (previous __syncthreads already fences all phase-1 LDS reads)
    if (t == 0) {
        lds[cbase] = sqrtf(s);                  // output 0 = sqrt(s0)
#pragma unroll
        for (int i = 0; i < CHUNK - 1; ++i) {
            s = fmaf(beta, s, fmaf(alpha, xr[i] * xr[i], omega));
            lds[cbase + 1 + i] = sqrtf(s);
        }
    } else {
        s = fmaf(beta, s, fmaf(alpha, prev * prev, omega));
        lds[cbase] = sqrtf(s);
#pragma unroll
        for (int i = 0; i < CHUNK - 1; ++i) {
            s = fmaf(beta, s, fmaf(alpha, xr[i] * xr[i], omega));
            lds[cbase + 1 + i] = sqrtf(s);
        }
    }
    __syncthreads();

    // ---- Phase 4: coalesced LDS -> global float4 stores ----
    float4* ov = reinterpret_cast<float4*>(out + rbase);
#pragma unroll
    for (int k = 0; k < 4; ++k) {
        int e4 = k * 1024 + 4 * t;
        int a0 = paddr(e4);
        float4 v;
        v.x = lds[a0 + 0]; v.y = lds[a0 + 1]; v.z = lds[a0 + 2]; v.w = lds[a0 + 3];
        ov[k * 256 + t] = v;
    }
}

extern "C" void kernel_launch(void* const* d_in, const int* in_sizes, int n_in,
                              void* d_out, int out_size, void* d_ws, size_t ws_size,
                              hipStream_t stream) {
    const float* x         = (const float*)d_in[0];
    const float* omega_log = (const float*)d_in[1];
    const float* alpha_log = (const float*)d_in[2];
    const float* beta_log  = (const float*)d_in[3];
    float* out = (float*)d_out;

    garch_fused<<<B_ROWS, NTHREADS, 0, stream>>>(x, omega_log, alpha_log, beta_log, out);
}